// Round 3
// baseline (178.639 us; speedup 1.0000x reference)
//
#include <hip/hip_runtime.h>
#include <hip/hip_bf16.h>

#define N_NODES  12288
#define N_FEAT   256
#define KDIM     128
#define N_GRAPHS 192
#define NMAX     112          // LDS fast-path max graph size (mean 64, std ~8)
#define KSTRIDE_U 68          // Kb LDS row stride in uints (272 B: staggered banks)

// workspace layout (bytes)
#define WS_STARTS 0
#define WS_WBUF   1024
#define WS_QG     (WS_WBUF + N_NODES * 4)             // fp32 Q [12288][128]
#define WS_KB     (WS_QG + N_NODES * KDIM * 4)        // bf16 K [12288][128] as u32[64]

__device__ __forceinline__ unsigned bf16_rne(float f) {
  unsigned u = __float_as_uint(f);
  return (u + 0x7FFFu + ((u >> 16) & 1u)) >> 16;
}
__device__ __forceinline__ float bf_lo(unsigned u) { return __uint_as_float(u << 16); }
__device__ __forceinline__ float bf_hi(unsigned u) { return __uint_as_float(u & 0xFFFF0000u); }

// ---------------------------------------------------------------------------
// Kernel 1: segment starts via binary search (batch is sorted).
// ---------------------------------------------------------------------------
__global__ __launch_bounds__(256) void seg_starts_k(const int* __restrict__ batch,
                                                    int* __restrict__ starts) {
  int g = threadIdx.x;
  if (g > N_GRAPHS) return;
  int lo = 0, hi = N_NODES;
  while (lo < hi) {
    int mid = (lo + hi) >> 1;
    if (batch[mid] < g) lo = mid + 1; else hi = mid;
  }
  starts[g] = lo;
}

// ---------------------------------------------------------------------------
// Kernel 2: fused Q|K projection. 768 blocks x 256 thr, 16-row slab (16 KB LDS
// -> 3 blocks/CU). Thread: 4 rows x {Q[2cc..],K[2cc..]}. Q fp32 (x 1/16),
// K written as packed bf16 (RNE) for the attention kernel.
// ---------------------------------------------------------------------------
__global__ __launch_bounds__(256) void qk_proj_k(const float* __restrict__ X,
                                                 const float* __restrict__ Wq,
                                                 const float* __restrict__ Wk,
                                                 float* __restrict__ Qg,
                                                 unsigned* __restrict__ Kb) {
  __shared__ float4 Xs4[16 * 64];   // 16 rows x 256 floats = 16 KB
  const int tid = threadIdx.x;
  const int cc  = tid & 63;         // column pair
  const int rg  = tid >> 6;         // row group (4 rows)
  const int r0  = blockIdx.x * 16;

  const float4* Xg4 = (const float4*)(X + (size_t)r0 * N_FEAT);
#pragma unroll
  for (int i = 0; i < 4; i++)
    Xs4[tid + i * 256] = Xg4[tid + i * 256];
  __syncthreads();

  float acc[4][4];
#pragma unroll
  for (int r = 0; r < 4; r++)
#pragma unroll
    for (int c = 0; c < 4; c++) acc[r][c] = 0.f;

#pragma unroll 4
  for (int kq = 0; kq < 64; kq++) {
    float2 wq[4], wk[4];
#pragma unroll
    for (int c = 0; c < 4; c++) {
      wq[c] = *(const float2*)&Wq[(4 * kq + c) * KDIM + 2 * cc];
      wk[c] = *(const float2*)&Wk[(4 * kq + c) * KDIM + 2 * cc];
    }
#pragma unroll
    for (int r = 0; r < 4; r++) {
      float4 x = Xs4[(rg * 4 + r) * 64 + kq];   // wave-broadcast read
      acc[r][0] = fmaf(x.x, wq[0].x, acc[r][0]);
      acc[r][1] = fmaf(x.x, wq[0].y, acc[r][1]);
      acc[r][2] = fmaf(x.x, wk[0].x, acc[r][2]);
      acc[r][3] = fmaf(x.x, wk[0].y, acc[r][3]);
      acc[r][0] = fmaf(x.y, wq[1].x, acc[r][0]);
      acc[r][1] = fmaf(x.y, wq[1].y, acc[r][1]);
      acc[r][2] = fmaf(x.y, wk[1].x, acc[r][2]);
      acc[r][3] = fmaf(x.y, wk[1].y, acc[r][3]);
      acc[r][0] = fmaf(x.z, wq[2].x, acc[r][0]);
      acc[r][1] = fmaf(x.z, wq[2].y, acc[r][1]);
      acc[r][2] = fmaf(x.z, wk[2].x, acc[r][2]);
      acc[r][3] = fmaf(x.z, wk[2].y, acc[r][3]);
      acc[r][0] = fmaf(x.w, wq[3].x, acc[r][0]);
      acc[r][1] = fmaf(x.w, wq[3].y, acc[r][1]);
      acc[r][2] = fmaf(x.w, wk[3].x, acc[r][2]);
      acc[r][3] = fmaf(x.w, wk[3].y, acc[r][3]);
    }
  }

#pragma unroll
  for (int r = 0; r < 4; r++) {
    int row = r0 + rg * 4 + r;
    *(float2*)&Qg[row * KDIM + 2 * cc] =
        make_float2(acc[r][0] * 0.0625f, acc[r][1] * 0.0625f);
    Kb[row * 64 + cc] = bf16_rne(acc[r][2]) | (bf16_rne(acc[r][3]) << 16);
  }
}

// ---------------------------------------------------------------------------
// Kernel 3: per-(graph, quarter) column weights of softmax(QK^T).
// 256 thr (4 waves). Wave-per-row: lanes = columns (j, j+64). K bf16 tile in
// LDS (272 B row stride), Q quarter fp32 in LDS read via broadcast. No
// barriers in the score loop; per-row shuffle softmax; w -> global atomics.
// Slow path (n > NMAX): qi==0 block, global K, two-pass online softmax.
// ---------------------------------------------------------------------------
__global__ __launch_bounds__(256) void attn_w_k(const int* __restrict__ starts,
                                                const float* __restrict__ Qg,
                                                const unsigned* __restrict__ Kb,
                                                float* __restrict__ wbuf) {
  __shared__ unsigned Ks_u[NMAX * KSTRIDE_U];   // 30464 B
  __shared__ float    Qs[28 * 128];             // 14336 B
  __shared__ float    w_lds[4][128];            // 2048 B

  const int tid  = threadIdx.x;
  const int lane = tid & 63;
  const int wv   = tid >> 6;
  const int g    = blockIdx.x >> 2;
  const int qi   = blockIdx.x & 3;

  const int i0 = starts[g];
  const int n  = starts[g + 1] - i0;
  const float BIG = 1e30f;
  const bool fast = (n <= NMAX);
  if (!fast && qi != 0) return;

  float wacc0 = 0.f, wacc1 = 0.f;

  if (fast) {
    const int qlen = (n + 3) >> 2;
    const int q0 = i0 + qi * qlen;
    const int q1 = min(i0 + n, q0 + qlen);
    const int rcount = q1 - q0;

    // ---- stage K (bf16) and Q quarter (fp32) ----
    for (int idx = tid; idx < n * 16; idx += 256) {
      int j = idx >> 4, c = idx & 15;
      *(uint4*)&Ks_u[j * KSTRIDE_U + 4 * c] = *(const uint4*)&Kb[(i0 + j) * 64 + 4 * c];
    }
    for (int idx = tid; idx < rcount * 32; idx += 256) {
      int r = idx >> 5, c = idx & 31;
      *(float4*)&Qs[r * 128 + 4 * c] = *(const float4*)&Qg[(q0 + r) * KDIM + 4 * c];
    }
    __syncthreads();

    const int j2c = min(64 + lane, NMAX - 1);
    const unsigned* kp1 = &Ks_u[lane * KSTRIDE_U];
    const unsigned* kp2 = &Ks_u[j2c * KSTRIDE_U];

    for (int lr = wv; lr < rcount; lr += 4) {
      const float* qp = &Qs[lr * 128];
      float s0 = 0.f, s1 = 0.f;
#pragma unroll
      for (int c = 0; c < 16; c++) {
        float4 qa = *(const float4*)&qp[8 * c];       // broadcast
        float4 qb = *(const float4*)&qp[8 * c + 4];   // broadcast
        uint4 K1 = *(const uint4*)&kp1[4 * c];
        uint4 K2 = *(const uint4*)&kp2[4 * c];
        s0 = fmaf(qa.x, bf_lo(K1.x), s0); s0 = fmaf(qa.y, bf_hi(K1.x), s0);
        s0 = fmaf(qa.z, bf_lo(K1.y), s0); s0 = fmaf(qa.w, bf_hi(K1.y), s0);
        s0 = fmaf(qb.x, bf_lo(K1.z), s0); s0 = fmaf(qb.y, bf_hi(K1.z), s0);
        s0 = fmaf(qb.z, bf_lo(K1.w), s0); s0 = fmaf(qb.w, bf_hi(K1.w), s0);
        s1 = fmaf(qa.x, bf_lo(K2.x), s1); s1 = fmaf(qa.y, bf_hi(K2.x), s1);
        s1 = fmaf(qa.z, bf_lo(K2.y), s1); s1 = fmaf(qa.w, bf_hi(K2.y), s1);
        s1 = fmaf(qb.x, bf_lo(K2.z), s1); s1 = fmaf(qb.y, bf_hi(K2.z), s1);
        s1 = fmaf(qb.z, bf_lo(K2.w), s1); s1 = fmaf(qb.w, bf_hi(K2.w), s1);
      }
      if (lane >= n)      s0 = -BIG;
      if (64 + lane >= n) s1 = -BIG;

      float m = fmaxf(s0, s1);
#pragma unroll
      for (int off = 32; off; off >>= 1) m = fmaxf(m, __shfl_xor(m, off));
      float e0 = __expf(s0 - m);
      float e1 = __expf(s1 - m);
      float l = e0 + e1;
#pragma unroll
      for (int off = 32; off; off >>= 1) l += __shfl_xor(l, off);
      float inv = 1.f / l;
      wacc0 += e0 * inv;
      wacc1 += e1 * inv;
    }
  } else {
    // ---- slow path: whole graph, global bf16 K, two-pass online softmax ----
    for (int lr = wv; lr < n; lr += 4) {
      const float* qp = &Qg[(i0 + lr) * KDIM];   // lane-uniform reads
      float m_run = -BIG, l_run = 0.f;
      for (int jb = 0; jb < n; jb += 64) {
        int j = jb + lane;
        int jc = min(j, n - 1);
        const unsigned* kp = &Kb[(i0 + jc) * 64];
        float s = 0.f;
        for (int c = 0; c < 16; c++) {
          float4 qa = *(const float4*)&qp[8 * c];
          float4 qb = *(const float4*)&qp[8 * c + 4];
          uint4 K1 = *(const uint4*)&kp[4 * c];
          s = fmaf(qa.x, bf_lo(K1.x), s); s = fmaf(qa.y, bf_hi(K1.x), s);
          s = fmaf(qa.z, bf_lo(K1.y), s); s = fmaf(qa.w, bf_hi(K1.y), s);
          s = fmaf(qb.x, bf_lo(K1.z), s); s = fmaf(qb.y, bf_hi(K1.z), s);
          s = fmaf(qb.z, bf_lo(K1.w), s); s = fmaf(qb.w, bf_hi(K1.w), s);
        }
        if (j >= n) s = -BIG;
        float mc = s;
        for (int off = 32; off; off >>= 1) mc = fmaxf(mc, __shfl_xor(mc, off));
        float m_new = fmaxf(m_run, mc);
        float lc = __expf(s - m_new);
        for (int off = 32; off; off >>= 1) lc += __shfl_xor(lc, off);
        l_run = l_run * __expf(m_run - m_new) + lc;
        m_run = m_new;
      }
      float inv = 1.f / l_run;
      for (int jb = 0; jb < n; jb += 64) {
        int j = jb + lane;
        int jc = min(j, n - 1);
        const unsigned* kp = &Kb[(i0 + jc) * 64];
        float s = 0.f;
        for (int c = 0; c < 16; c++) {
          float4 qa = *(const float4*)&qp[8 * c];
          float4 qb = *(const float4*)&qp[8 * c + 4];
          uint4 K1 = *(const uint4*)&kp[4 * c];
          s = fmaf(qa.x, bf_lo(K1.x), s); s = fmaf(qa.y, bf_hi(K1.x), s);
          s = fmaf(qa.z, bf_lo(K1.y), s); s = fmaf(qa.w, bf_hi(K1.y), s);
          s = fmaf(qb.x, bf_lo(K1.z), s); s = fmaf(qb.y, bf_hi(K1.z), s);
          s = fmaf(qb.z, bf_lo(K1.w), s); s = fmaf(qb.w, bf_hi(K1.w), s);
        }
        if (j < n) atomicAdd(&wbuf[i0 + j], __expf(s - m_run) * inv);
      }
    }
  }

  // ---- combine per-wave column weights, add into global wbuf ----
  w_lds[wv][lane] = wacc0;
  w_lds[wv][64 + lane] = wacc1;
  __syncthreads();
  if (tid < 128) {
    float t = w_lds[0][tid] + w_lds[1][tid] + w_lds[2][tid] + w_lds[3][tid];
    if (tid < n && t != 0.f) atomicAdd(&wbuf[i0 + tid], t);
  }
}

// ---------------------------------------------------------------------------
// Kernel 4: out[g] = (w^T X_g) @ Wv.  192 blocks x 512 thr.
// ---------------------------------------------------------------------------
__global__ __launch_bounds__(512) void vout_k(const float* __restrict__ X,
                                              const int* __restrict__ starts,
                                              const float* __restrict__ wbuf,
                                              const float* __restrict__ Wv,
                                              float* __restrict__ out) {
  __shared__ float Us[256];
  __shared__ float part[256];
  const int g    = blockIdx.x;
  const int tid  = threadIdx.x;
  const int f    = tid & 255;
  const int half = tid >> 8;

  const int i0 = starts[g];
  const int n  = starts[g + 1] - i0;

  // u[f] = sum_j w_j * X[i0+j][f]  (j split by half)
  float ua = 0.f;
  for (int j = half; j < n; j += 2)
    ua = fmaf(wbuf[i0 + j], X[(size_t)(i0 + j) * N_FEAT + f], ua);
  if (half == 1) part[f] = ua;
  __syncthreads();
  if (half == 0) Us[f] = ua + part[f];
  __syncthreads();

  // out[f] = sum_k u_k * Wv[k][f]  (k split by half)
  const float* wp = Wv + (size_t)half * 128 * N_FEAT + f;
  const float* us = &Us[half * 128];
  float a0 = 0.f, a1 = 0.f, a2 = 0.f, a3 = 0.f;
#pragma unroll 8
  for (int k = 0; k < 128; k += 4) {
    a0 = fmaf(us[k],     wp[(size_t)k * N_FEAT], a0);
    a1 = fmaf(us[k + 1], wp[(size_t)(k + 1) * N_FEAT], a1);
    a2 = fmaf(us[k + 2], wp[(size_t)(k + 2) * N_FEAT], a2);
    a3 = fmaf(us[k + 3], wp[(size_t)(k + 3) * N_FEAT], a3);
  }
  float acc = (a0 + a1) + (a2 + a3);
  __syncthreads();
  if (half == 1) part[f] = acc;
  __syncthreads();
  if (half == 0) out[g * N_FEAT + f] = acc + part[f];
}

// ---------------------------------------------------------------------------
extern "C" void kernel_launch(void* const* d_in, const int* in_sizes, int n_in,
                              void* d_out, int out_size, void* d_ws, size_t ws_size,
                              hipStream_t stream) {
  const float* X     = (const float*)d_in[0];
  const int*   batch = (const int*)d_in[1];
  const float* Wq    = (const float*)d_in[2];
  const float* Wk    = (const float*)d_in[3];
  const float* Wv    = (const float*)d_in[4];
  float* out = (float*)d_out;

  char* ws = (char*)d_ws;
  int*      starts = (int*)(ws + WS_STARTS);
  float*    wbuf   = (float*)(ws + WS_WBUF);
  float*    Qg     = (float*)(ws + WS_QG);
  unsigned* Kb     = (unsigned*)(ws + WS_KB);

  hipMemsetAsync(wbuf, 0, N_NODES * 4, stream);
  seg_starts_k<<<1, 256, 0, stream>>>(batch, starts);
  qk_proj_k<<<N_NODES / 16, 256, 0, stream>>>(X, Wq, Wk, Qg, Kb);
  attn_w_k<<<N_GRAPHS * 4, 256, 0, stream>>>(starts, Qg, Kb, wbuf);
  vout_k<<<N_GRAPHS, 512, 0, stream>>>(X, starts, wbuf, Wv, out);
}

// Round 4
// 142.866 us; speedup vs baseline: 1.2504x; 1.2504x over previous
//
#include <hip/hip_runtime.h>
#include <hip/hip_bf16.h>

#define N_NODES  12288
#define N_FEAT   256
#define KDIM     128
#define N_GRAPHS 192
#define NMAX     112          // LDS fast-path max graph size (mean 64, std ~8)
#define KSTRIDE_U 68          // Kb LDS row stride in uints (272 B: staggered banks)

// qk_proj MFMA tile params
#define MT   32               // rows per block
#define XS_STRIDE_U 36        // X LDS row stride in u32 (72 bf16; 36%32=4 -> balanced)
#define WT_STRIDE_U 36        // Wt LDS row stride in u32

// workspace layout (bytes)
#define WS_STARTS 0
#define WS_WBUF   1024
#define WS_QG     (WS_WBUF + N_NODES * 4)             // fp32 Q [12288][128]
#define WS_KB     (WS_QG + N_NODES * KDIM * 4)        // bf16 K [12288][128] as u32[64]
#define WS_WT     (WS_KB + N_NODES * 64 * 4)          // bf16 Wt [256 n][256 k] as u32[128]

typedef __bf16 bf16x8 __attribute__((ext_vector_type(8)));
typedef float  f32x4  __attribute__((ext_vector_type(4)));

__device__ __forceinline__ unsigned bf16_rne(float f) {
  unsigned u = __float_as_uint(f);
  return (u + 0x7FFFu + ((u >> 16) & 1u)) >> 16;
}
__device__ __forceinline__ unsigned pack_bf16(float lo, float hi) {
  return bf16_rne(lo) | (bf16_rne(hi) << 16);
}
__device__ __forceinline__ float bf_lo(unsigned u) { return __uint_as_float(u << 16); }
__device__ __forceinline__ float bf_hi(unsigned u) { return __uint_as_float(u & 0xFFFF0000u); }

// ---------------------------------------------------------------------------
// Kernel 1: segment starts via binary search (batch is sorted).
// ---------------------------------------------------------------------------
__global__ __launch_bounds__(256) void seg_starts_k(const int* __restrict__ batch,
                                                    int* __restrict__ starts) {
  int g = threadIdx.x;
  if (g > N_GRAPHS) return;
  int lo = 0, hi = N_NODES;
  while (lo < hi) {
    int mid = (lo + hi) >> 1;
    if (batch[mid] < g) lo = mid + 1; else hi = mid;
  }
  starts[g] = lo;
}

// ---------------------------------------------------------------------------
// Kernel 1b: W pre-transpose to bf16.  Wt[n][k] packed u32 pairs (k, k+1).
// n < 128 -> Wq column n; n >= 128 -> Wk column n-128.  256 blocks x 64 thr.
// ---------------------------------------------------------------------------
__global__ __launch_bounds__(64) void wt_prep_k(const float* __restrict__ Wq,
                                                const float* __restrict__ Wk,
                                                unsigned* __restrict__ Wt) {
  const int n = blockIdx.x;
  const int t = threadIdx.x;
  const float* src = (n < KDIM) ? (Wq + n) : (Wk + (n - KDIM));
  float f0 = src[(4 * t + 0) * KDIM];
  float f1 = src[(4 * t + 1) * KDIM];
  float f2 = src[(4 * t + 2) * KDIM];
  float f3 = src[(4 * t + 3) * KDIM];
  Wt[n * 128 + 2 * t]     = pack_bf16(f0, f1);
  Wt[n * 128 + 2 * t + 1] = pack_bf16(f2, f3);
}

// ---------------------------------------------------------------------------
// Kernel 2: fused Q|K projection via bf16 MFMA.
// 384 blocks x 256 thr (4 waves). M-tile 32, N = 256 (wave w owns cols
// 64w..64w+63; waves 0-1 -> Q, 2-3 -> K). K = 256 in 4 chunks of 64.
// LDS: X chunk [32][64] bf16 + Wt chunk [256][64] bf16, row stride 72 bf16
// (36 dwords == 4 mod 32 -> frag b128 reads sit exactly at the BW floor).
// Q written fp32 (x 1/16); K written packed bf16 (RNE, shfl-paired).
// ---------------------------------------------------------------------------
__global__ __launch_bounds__(256) void qk_proj_k(const float* __restrict__ X,
                                                 const unsigned* __restrict__ Wt,
                                                 float* __restrict__ Qg,
                                                 unsigned* __restrict__ Kb) {
  __shared__ unsigned Xs_u[MT * XS_STRIDE_U];      // 4608 B
  __shared__ unsigned Ws_u[256 * WT_STRIDE_U];     // 36864 B

  const int tid  = threadIdx.x;
  const int lane = tid & 63;
  const int wv   = tid >> 6;
  const int r0   = blockIdx.x * MT;
  const int l15  = lane & 15;
  const int quad = lane >> 4;

  f32x4 acc[2][4];
#pragma unroll
  for (int mi = 0; mi < 2; mi++)
#pragma unroll
    for (int ni = 0; ni < 4; ni++) acc[mi][ni] = (f32x4){0.f, 0.f, 0.f, 0.f};

  for (int c = 0; c < 4; c++) {
    const int k0 = c * 64;
    if (c) __syncthreads();

    // ---- stage X chunk: 32 rows x 64 k, fp32 -> bf16 ----
    {
      const int row = tid >> 3, c8 = tid & 7;   // 8 bf16 per thread
      const float* xp = &X[(size_t)(r0 + row) * N_FEAT + k0 + c8 * 8];
      float4 a = *(const float4*)xp;
      float4 b = *(const float4*)(xp + 4);
      unsigned p0 = pack_bf16(a.x, a.y), p1 = pack_bf16(a.z, a.w);
      unsigned p2 = pack_bf16(b.x, b.y), p3 = pack_bf16(b.z, b.w);
      *(uint4*)&Xs_u[row * XS_STRIDE_U + c8 * 4] = make_uint4(p0, p1, p2, p3);
    }
    // ---- stage Wt chunk: 256 n-rows x 64 k (bf16 packed) ----
#pragma unroll
    for (int it = 0; it < 8; it++) {
      const int i = tid + it * 256;
      const int n = i >> 3, c8 = i & 7;
      uint4 w = *(const uint4*)&Wt[n * 128 + k0 / 2 + c8 * 4];
      *(uint4*)&Ws_u[n * WT_STRIDE_U + c8 * 4] = w;
    }
    __syncthreads();

    // ---- MFMA: 2 m-tiles x 4 n-tiles x 2 k-steps ----
#pragma unroll
    for (int ks = 0; ks < 2; ks++) {
      const int ko = ks * 16 + quad * 4;   // u32 offset within row
      bf16x8 a[2], b[4];
#pragma unroll
      for (int mi = 0; mi < 2; mi++)
        a[mi] = *(const bf16x8*)&Xs_u[(mi * 16 + l15) * XS_STRIDE_U + ko];
#pragma unroll
      for (int ni = 0; ni < 4; ni++)
        b[ni] = *(const bf16x8*)&Ws_u[(wv * 64 + ni * 16 + l15) * WT_STRIDE_U + ko];
#pragma unroll
      for (int mi = 0; mi < 2; mi++)
#pragma unroll
        for (int ni = 0; ni < 4; ni++)
          acc[mi][ni] = __builtin_amdgcn_mfma_f32_16x16x32_bf16(a[mi], b[ni], acc[mi][ni], 0, 0, 0);
    }
  }

  // ---- epilogue: C/D layout col = lane&15, row = quad*4 + e ----
  if (wv < 2) {
    // Q columns (0..127), fp32 x 1/16
#pragma unroll
    for (int mi = 0; mi < 2; mi++)
#pragma unroll
      for (int ni = 0; ni < 4; ni++) {
        const int col = wv * 64 + ni * 16 + l15;
#pragma unroll
        for (int e = 0; e < 4; e++) {
          const int row = r0 + mi * 16 + quad * 4 + e;
          Qg[row * KDIM + col] = acc[mi][ni][e] * 0.0625f;
        }
      }
  } else {
    // K columns (0..127), packed bf16 pairs via lane pairing
#pragma unroll
    for (int mi = 0; mi < 2; mi++)
#pragma unroll
      for (int ni = 0; ni < 4; ni++) {
        const int col = (wv - 2) * 64 + ni * 16 + l15;
#pragma unroll
        for (int e = 0; e < 4; e++) {
          const int row = r0 + mi * 16 + quad * 4 + e;
          unsigned b = bf16_rne(acc[mi][ni][e]);
          unsigned partner = __shfl_xor((int)b, 1);
          if ((lane & 1) == 0)
            Kb[row * 64 + (col >> 1)] = b | (partner << 16);
        }
      }
  }
}

// ---------------------------------------------------------------------------
// Kernel 3: per-(graph, quarter) column weights of softmax(QK^T).
// 256 thr (4 waves). Wave-per-row: lanes = columns (j, j+64). K bf16 tile in
// LDS (272 B row stride), Q quarter fp32 in LDS read via broadcast.
// Slow path (n > NMAX): qi==0 block, global K, two-pass online softmax.
// ---------------------------------------------------------------------------
__global__ __launch_bounds__(256) void attn_w_k(const int* __restrict__ starts,
                                                const float* __restrict__ Qg,
                                                const unsigned* __restrict__ Kb,
                                                float* __restrict__ wbuf) {
  __shared__ unsigned Ks_u[NMAX * KSTRIDE_U];   // 30464 B
  __shared__ float    Qs[28 * 128];             // 14336 B
  __shared__ float    w_lds[4][128];            // 2048 B

  const int tid  = threadIdx.x;
  const int lane = tid & 63;
  const int wv   = tid >> 6;
  const int g    = blockIdx.x >> 2;
  const int qi   = blockIdx.x & 3;

  const int i0 = starts[g];
  const int n  = starts[g + 1] - i0;
  const float BIG = 1e30f;
  const bool fast = (n <= NMAX);
  if (!fast && qi != 0) return;

  float wacc0 = 0.f, wacc1 = 0.f;

  if (fast) {
    const int qlen = (n + 3) >> 2;
    const int q0 = i0 + qi * qlen;
    const int q1 = min(i0 + n, q0 + qlen);
    const int rcount = q1 - q0;

    for (int idx = tid; idx < n * 16; idx += 256) {
      int j = idx >> 4, c = idx & 15;
      *(uint4*)&Ks_u[j * KSTRIDE_U + 4 * c] = *(const uint4*)&Kb[(i0 + j) * 64 + 4 * c];
    }
    for (int idx = tid; idx < rcount * 32; idx += 256) {
      int r = idx >> 5, c = idx & 31;
      *(float4*)&Qs[r * 128 + 4 * c] = *(const float4*)&Qg[(q0 + r) * KDIM + 4 * c];
    }
    __syncthreads();

    const int j2c = min(64 + lane, NMAX - 1);
    const unsigned* kp1 = &Ks_u[lane * KSTRIDE_U];
    const unsigned* kp2 = &Ks_u[j2c * KSTRIDE_U];

    for (int lr = wv; lr < rcount; lr += 4) {
      const float* qp = &Qs[lr * 128];
      float s0 = 0.f, s1 = 0.f;
#pragma unroll
      for (int c = 0; c < 16; c++) {
        float4 qa = *(const float4*)&qp[8 * c];
        float4 qb = *(const float4*)&qp[8 * c + 4];
        uint4 K1 = *(const uint4*)&kp1[4 * c];
        uint4 K2 = *(const uint4*)&kp2[4 * c];
        s0 = fmaf(qa.x, bf_lo(K1.x), s0); s0 = fmaf(qa.y, bf_hi(K1.x), s0);
        s0 = fmaf(qa.z, bf_lo(K1.y), s0); s0 = fmaf(qa.w, bf_hi(K1.y), s0);
        s0 = fmaf(qb.x, bf_lo(K1.z), s0); s0 = fmaf(qb.y, bf_hi(K1.z), s0);
        s0 = fmaf(qb.z, bf_lo(K1.w), s0); s0 = fmaf(qb.w, bf_hi(K1.w), s0);
        s1 = fmaf(qa.x, bf_lo(K2.x), s1); s1 = fmaf(qa.y, bf_hi(K2.x), s1);
        s1 = fmaf(qa.z, bf_lo(K2.y), s1); s1 = fmaf(qa.w, bf_hi(K2.y), s1);
        s1 = fmaf(qb.x, bf_lo(K2.z), s1); s1 = fmaf(qb.y, bf_hi(K2.z), s1);
        s1 = fmaf(qb.z, bf_lo(K2.w), s1); s1 = fmaf(qb.w, bf_hi(K2.w), s1);
      }
      if (lane >= n)      s0 = -BIG;
      if (64 + lane >= n) s1 = -BIG;

      float m = fmaxf(s0, s1);
#pragma unroll
      for (int off = 32; off; off >>= 1) m = fmaxf(m, __shfl_xor(m, off));
      float e0 = __expf(s0 - m);
      float e1 = __expf(s1 - m);
      float l = e0 + e1;
#pragma unroll
      for (int off = 32; off; off >>= 1) l += __shfl_xor(l, off);
      float inv = 1.f / l;
      wacc0 += e0 * inv;
      wacc1 += e1 * inv;
    }
  } else {
    for (int lr = wv; lr < n; lr += 4) {
      const float* qp = &Qg[(i0 + lr) * KDIM];
      float m_run = -BIG, l_run = 0.f;
      for (int jb = 0; jb < n; jb += 64) {
        int j = jb + lane;
        int jc = min(j, n - 1);
        const unsigned* kp = &Kb[(i0 + jc) * 64];
        float s = 0.f;
        for (int c = 0; c < 16; c++) {
          float4 qa = *(const float4*)&qp[8 * c];
          float4 qb = *(const float4*)&qp[8 * c + 4];
          uint4 K1 = *(const uint4*)&kp[4 * c];
          s = fmaf(qa.x, bf_lo(K1.x), s); s = fmaf(qa.y, bf_hi(K1.x), s);
          s = fmaf(qa.z, bf_lo(K1.y), s); s = fmaf(qa.w, bf_hi(K1.y), s);
          s = fmaf(qb.x, bf_lo(K1.z), s); s = fmaf(qb.y, bf_hi(K1.z), s);
          s = fmaf(qb.z, bf_lo(K1.w), s); s = fmaf(qb.w, bf_hi(K1.w), s);
        }
        if (j >= n) s = -BIG;
        float mc = s;
        for (int off = 32; off; off >>= 1) mc = fmaxf(mc, __shfl_xor(mc, off));
        float m_new = fmaxf(m_run, mc);
        float lc = __expf(s - m_new);
        for (int off = 32; off; off >>= 1) lc += __shfl_xor(lc, off);
        l_run = l_run * __expf(m_run - m_new) + lc;
        m_run = m_new;
      }
      float inv = 1.f / l_run;
      for (int jb = 0; jb < n; jb += 64) {
        int j = jb + lane;
        int jc = min(j, n - 1);
        const unsigned* kp = &Kb[(i0 + jc) * 64];
        float s = 0.f;
        for (int c = 0; c < 16; c++) {
          float4 qa = *(const float4*)&qp[8 * c];
          float4 qb = *(const float4*)&qp[8 * c + 4];
          uint4 K1 = *(const uint4*)&kp[4 * c];
          s = fmaf(qa.x, bf_lo(K1.x), s); s = fmaf(qa.y, bf_hi(K1.x), s);
          s = fmaf(qa.z, bf_lo(K1.y), s); s = fmaf(qa.w, bf_hi(K1.y), s);
          s = fmaf(qb.x, bf_lo(K1.z), s); s = fmaf(qb.y, bf_hi(K1.z), s);
          s = fmaf(qb.z, bf_lo(K1.w), s); s = fmaf(qb.w, bf_hi(K1.w), s);
        }
        if (j < n) atomicAdd(&wbuf[i0 + j], __expf(s - m_run) * inv);
      }
    }
  }

  w_lds[wv][lane] = wacc0;
  w_lds[wv][64 + lane] = wacc1;
  __syncthreads();
  if (tid < 128) {
    float t = w_lds[0][tid] + w_lds[1][tid] + w_lds[2][tid] + w_lds[3][tid];
    if (tid < n && t != 0.f) atomicAdd(&wbuf[i0 + tid], t);
  }
}

// ---------------------------------------------------------------------------
// Kernel 4: out[g] = (w^T X_g) @ Wv.  192 blocks x 512 thr.
// ---------------------------------------------------------------------------
__global__ __launch_bounds__(512) void vout_k(const float* __restrict__ X,
                                              const int* __restrict__ starts,
                                              const float* __restrict__ wbuf,
                                              const float* __restrict__ Wv,
                                              float* __restrict__ out) {
  __shared__ float Us[256];
  __shared__ float part[256];
  const int g    = blockIdx.x;
  const int tid  = threadIdx.x;
  const int f    = tid & 255;
  const int half = tid >> 8;

  const int i0 = starts[g];
  const int n  = starts[g + 1] - i0;

  float ua = 0.f;
  for (int j = half; j < n; j += 2)
    ua = fmaf(wbuf[i0 + j], X[(size_t)(i0 + j) * N_FEAT + f], ua);
  if (half == 1) part[f] = ua;
  __syncthreads();
  if (half == 0) Us[f] = ua + part[f];
  __syncthreads();

  const float* wp = Wv + (size_t)half * 128 * N_FEAT + f;
  const float* us = &Us[half * 128];
  float a0 = 0.f, a1 = 0.f, a2 = 0.f, a3 = 0.f;
#pragma unroll 8
  for (int k = 0; k < 128; k += 4) {
    a0 = fmaf(us[k],     wp[(size_t)k * N_FEAT], a0);
    a1 = fmaf(us[k + 1], wp[(size_t)(k + 1) * N_FEAT], a1);
    a2 = fmaf(us[k + 2], wp[(size_t)(k + 2) * N_FEAT], a2);
    a3 = fmaf(us[k + 3], wp[(size_t)(k + 3) * N_FEAT], a3);
  }
  float acc = (a0 + a1) + (a2 + a3);
  __syncthreads();
  if (half == 1) part[f] = acc;
  __syncthreads();
  if (half == 0) out[g * N_FEAT + f] = acc + part[f];
}

// ---------------------------------------------------------------------------
extern "C" void kernel_launch(void* const* d_in, const int* in_sizes, int n_in,
                              void* d_out, int out_size, void* d_ws, size_t ws_size,
                              hipStream_t stream) {
  const float* X     = (const float*)d_in[0];
  const int*   batch = (const int*)d_in[1];
  const float* Wq    = (const float*)d_in[2];
  const float* Wk    = (const float*)d_in[3];
  const float* Wv    = (const float*)d_in[4];
  float* out = (float*)d_out;

  char* ws = (char*)d_ws;
  int*      starts = (int*)(ws + WS_STARTS);
  float*    wbuf   = (float*)(ws + WS_WBUF);
  float*    Qg     = (float*)(ws + WS_QG);
  unsigned* Kb     = (unsigned*)(ws + WS_KB);
  unsigned* Wt     = (unsigned*)(ws + WS_WT);

  hipMemsetAsync(wbuf, 0, N_NODES * 4, stream);
  seg_starts_k<<<1, 256, 0, stream>>>(batch, starts);
  wt_prep_k<<<256, 64, 0, stream>>>(Wq, Wk, Wt);
  qk_proj_k<<<N_NODES / MT, 256, 0, stream>>>(X, Wt, Qg, Kb);
  attn_w_k<<<N_GRAPHS * 4, 256, 0, stream>>>(starts, Qg, Kb, wbuf);
  vout_k<<<N_GRAPHS, 512, 0, stream>>>(X, starts, wbuf, Wv, out);
}